// Round 1
// 877.029 us; speedup vs baseline: 1.0034x; 1.0034x over previous
//
#include <hip/hip_runtime.h>
#include <math.h>

#define N_NODES 100000
#define N_EDGES 3200000
#define F_IN    512
#define F1      16
#define F2      40

#define N_BUCKETS 6250    // node>>4 buckets; 6250*16 == 100000 exactly
#define NPART     8       // writer partitions (one per XCD under round-robin blockIdx map)
#define CAPP      120     // per (bucket,part) capacity; mean 64, sigma 8 -> 7 sigma
#define OCAP      32      // per-bucket overflow segment (shared across parts)

// mm1 tiling
#define BR 256            // rows per block
#define KK 32             // k-chunk
#define XPITCH 36         // 32 + 4 pad: 2-way LDS alias max (free)

// ------- layer-1 matmul, LDS-tiled: h1t[r] = dis[r]*(x[r]@W1 + b1) -------
__global__ __launch_bounds__(256, 4) void mm1_kernel(
        const float* __restrict__ x, const float* __restrict__ W1,
        const float* __restrict__ b1, const float* __restrict__ dis,
        float* __restrict__ h1t) {
    __shared__ float xs[BR * XPITCH];     // 36 KB
    __shared__ float ws[KK * F1];         // 2 KB
    int t = threadIdx.x;
    int rbase = blockIdx.x * BR;
    int jq = t & 3;            // j-quad: cols jq*4..jq*4+3
    int rg = t >> 2;           // row-group 0..63: rows rg*4..rg*4+3
    float acc[4][4];
#pragma unroll
    for (int i = 0; i < 4; ++i)
#pragma unroll
        for (int j = 0; j < 4; ++j) acc[i][j] = 0.0f;

    for (int ch = 0; ch < F_IN / KK; ++ch) {
        int c0 = ch * KK;
#pragma unroll
        for (int i = 0; i < 8; ++i) {
            int p  = t + i * 256;
            int tr = p >> 3;
            int f4 = p & 7;
            float4 v = make_float4(0.0f, 0.0f, 0.0f, 0.0f);
            int grow = rbase + tr;
            if (grow < N_NODES)
                v = *(const float4*)(x + (size_t)grow * F_IN + c0 + f4 * 4);
            *(float4*)&xs[tr * XPITCH + f4 * 4] = v;
        }
        if (t < 128) {
            int kk = t >> 2, f4 = t & 3;
            *(float4*)&ws[kk * F1 + f4 * 4] =
                *(const float4*)(W1 + (size_t)(c0 + kk) * F1 + f4 * 4);
        }
        __syncthreads();
#pragma unroll
        for (int k4 = 0; k4 < KK / 4; ++k4) {
            float xa[4][4], wa[4][4];
#pragma unroll
            for (int i = 0; i < 4; ++i)
                *(float4*)&xa[i][0] =
                    *(const float4*)&xs[(rg * 4 + i) * XPITCH + k4 * 4];
#pragma unroll
            for (int m = 0; m < 4; ++m)
                *(float4*)&wa[m][0] =
                    *(const float4*)&ws[(k4 * 4 + m) * F1 + jq * 4];
#pragma unroll
            for (int i = 0; i < 4; ++i)
#pragma unroll
                for (int m = 0; m < 4; ++m)
#pragma unroll
                    for (int j = 0; j < 4; ++j)
                        acc[i][j] = fmaf(xa[i][m], wa[m][j], acc[i][j]);
        }
        __syncthreads();
    }

    float4 bv = *(const float4*)(b1 + jq * 4);
#pragma unroll
    for (int i = 0; i < 4; ++i) {
        int grow = rbase + rg * 4 + i;
        if (grow < N_NODES) {
            float d = dis[grow];
            float4 o;
            o.x = d * (acc[i][0] + bv.x);
            o.y = d * (acc[i][1] + bv.y);
            o.z = d * (acc[i][2] + bv.z);
            o.w = d * (acc[i][3] + bv.w);
            *(float4*)(h1t + (size_t)grow * F1 + jq * 4) = o;
        }
    }
}

// ---------------- init: zero deg + cursors -------------------------------
__global__ void init_kernel(int* __restrict__ deg, int* __restrict__ bcur,
                            int* __restrict__ ocur) {
    int i = blockIdx.x * blockDim.x + threadIdx.x;
    if (i < N_NODES) deg[i] = 0;
    if (i < N_BUCKETS * NPART) bcur[i] = 0;
    if (i < N_BUCKETS) ocur[i] = 0;
}

// ---- single pass: bin edges by col>>4 (payload r|low4(c)) into WRITER-
// PARTITIONED staging (part = blockIdx&7 -> one XCD per part under the
// round-robin block->XCD map), so each tail line is dirtied by exactly one
// L2 and evicted once when full. Degrees via direct L2 atomics (replaces
// the old staging_r byte-append + deg_kernel pass, both write-amplified).
__global__ void bin_kernel(const int* __restrict__ row, const int* __restrict__ col,
                           int* __restrict__ deg,
                           int* __restrict__ bcur, int* __restrict__ ocur,
                           int* __restrict__ staging, int* __restrict__ staging_o) {
    int e = blockIdx.x * blockDim.x + threadIdx.x;
    if (e >= N_EDGES) return;
    int part = blockIdx.x & (NPART - 1);
    int r = row[e];
    int c = col[e];
    atomicAdd(&deg[r], 1);
    int bc = c >> 4;
    int payload = r | ((c & 15) << 27);
    int cell = bc * NPART + part;
    int pc = atomicAdd(&bcur[cell], 1);
    if (pc < CAPP) {
        staging[(size_t)cell * CAPP + pc] = payload;
    } else {
        int po = atomicAdd(&ocur[bc], 1);
        if (po < OCAP) staging_o[(size_t)bc * OCAP + po] = payload;
    }
}

// ---- dis = (deg+1)^-0.5 (+1 for self loop) ------------------------------
__global__ void dis_kernel(const int* __restrict__ deg, float* __restrict__ dis) {
    int i = blockIdx.x * blockDim.x + threadIdx.x;
    if (i < N_NODES) dis[i] = rsqrtf((float)(deg[i] + 1));
}

// ---- exclusive scan of 6250 bucket sizes -> bucket_start (one block) ----
__global__ void scanb_kernel(const int* __restrict__ bcur, const int* __restrict__ ocur,
                             int* __restrict__ bucket_start) {
    __shared__ int lds[256];
    int t = threadIdx.x;
    int base = t * 25;                 // 256*25 = 6400 >= 6250
    int s = 0;
    for (int i = 0; i < 25; ++i) {
        int idx = base + i;
        if (idx < N_BUCKETS) {
            int tot = min(ocur[idx], OCAP);
#pragma unroll
            for (int p = 0; p < NPART; ++p) tot += min(bcur[idx * NPART + p], CAPP);
            s += tot;
        }
    }
    lds[t] = s;
    __syncthreads();
    for (int off = 1; off < 256; off <<= 1) {
        int v = (t >= off) ? lds[t - off] : 0;
        __syncthreads();
        lds[t] += v;
        __syncthreads();
    }
    int run = lds[t] - s;              // exclusive prefix
    for (int i = 0; i < 25; ++i) {
        int idx = base + i;
        if (idx < N_BUCKETS) {
            bucket_start[idx] = run;
            int tot = min(ocur[idx], OCAP);
#pragma unroll
            for (int p = 0; p < NPART; ++p) tot += min(bcur[idx * NPART + p], CAPP);
            run += tot;
        }
    }
}

// ---- per-bucket CSR finalize: 16-bin LDS histogram + scan + scatter -----
// Reads the bucket's 8 contiguous part segments + overflow; writes
// start/cnt for the bucket's 16 cols and rows_sorted in a contiguous
// ~2KB window (single-block ownership -> no cross-XCD line churn).
__global__ void csr_kernel(const int* __restrict__ staging, const int* __restrict__ staging_o,
                           const int* __restrict__ bcur, const int* __restrict__ ocur,
                           const int* __restrict__ bucket_start,
                           int* __restrict__ start, int* __restrict__ cnt,
                           int* __restrict__ rows_sorted) {
    __shared__ int cnt16[16], off16[16], cur16[16];
    int b = blockIdx.x, t = threadIdx.x;
    if (t < 16) cnt16[t] = 0;
    __syncthreads();
    const int* sb = staging + (size_t)b * NPART * CAPP;
    int szs[NPART];
#pragma unroll
    for (int p = 0; p < NPART; ++p) szs[p] = min(bcur[b * NPART + p], CAPP);
    int szo = min(ocur[b], OCAP);
    const int* so = staging_o + (size_t)b * OCAP;
#pragma unroll
    for (int p = 0; p < NPART; ++p)
        for (int k = t; k < szs[p]; k += 256)
            atomicAdd(&cnt16[(sb[p * CAPP + k] >> 27) & 15], 1);
    for (int k = t; k < szo; k += 256)
        atomicAdd(&cnt16[(so[k] >> 27) & 15], 1);
    __syncthreads();
    if (t == 0) {
        int s = 0;
#pragma unroll
        for (int i = 0; i < 16; ++i) { off16[i] = s; s += cnt16[i]; }
    }
    __syncthreads();
    int base = bucket_start[b];
    if (t < 16) {
        start[b * 16 + t] = base + off16[t];
        cnt[b * 16 + t]   = cnt16[t];
        cur16[t] = 0;
    }
    __syncthreads();
#pragma unroll
    for (int p = 0; p < NPART; ++p)
        for (int k = t; k < szs[p]; k += 256) {
            int entry = sb[p * CAPP + k];
            int c4 = (entry >> 27) & 15;
            int pos = atomicAdd(&cur16[c4], 1);
            rows_sorted[base + off16[c4] + pos] = entry & 0x07FFFFFF;
        }
    for (int k = t; k < szo; k += 256) {
        int entry = so[k];
        int c4 = (entry >> 27) & 15;
        int pos = atomicAdd(&cur16[c4], 1);
        rows_sorted[base + off16[c4] + pos] = entry & 0x07FFFFFF;
    }
}

// ------- layer-1 aggregation (dis-folded) + relu + row-sum s -------------
__global__ void agg1_kernel(const int* __restrict__ rows_sorted,
                            const int* __restrict__ start, const int* __restrict__ cnt,
                            const float* __restrict__ dis, const float* __restrict__ h1t,
                            float* __restrict__ g, float* __restrict__ s_out) {
    int idx = blockIdx.x * blockDim.x + threadIdx.x;
    if (idx >= N_NODES * 4) return;
    int c = idx >> 2;
    int q = idx & 3;
    float dc = dis[c];
    const float4* h4 = (const float4*)h1t;
    float4 acc = h4[(size_t)c * 4 + q];          // self loop: h1t[c] = dc*h1[c]
    float ss = dc;
    int k0 = start[c];
    int k1 = k0 + cnt[c];
    for (int k = k0; k < k1; ++k) {
        int r = rows_sorted[k];
        float4 v = h4[(size_t)r * 4 + q];
        acc.x += v.x; acc.y += v.y; acc.z += v.z; acc.w += v.w;
        if (q == 0) ss += dis[r];                // lane q=0 gathers dis (L2-hot)
    }
    acc.x = dc * fmaxf(acc.x * dc, 0.0f);        // relu, then fold dc for layer 2
    acc.y = dc * fmaxf(acc.y * dc, 0.0f);
    acc.z = dc * fmaxf(acc.z * dc, 0.0f);
    acc.w = dc * fmaxf(acc.w * dc, 0.0f);
    ((float4*)g)[(size_t)c * 4 + q] = acc;
    if (q == 0) s_out[c] = dc * ss;              // s = (A_hat . 1)[c]
}

// ---------------- layer-2 aggregation (dis-folded): t = A_hat g ----------
__global__ void agg2_kernel(const int* __restrict__ rows_sorted,
                            const int* __restrict__ start, const int* __restrict__ cnt,
                            const float* __restrict__ dis, const float* __restrict__ g,
                            float* __restrict__ t) {
    int idx = blockIdx.x * blockDim.x + threadIdx.x;
    if (idx >= N_NODES * 4) return;
    int c = idx >> 2;
    int q = idx & 3;
    float dc = dis[c];
    const float4* h4 = (const float4*)g;
    float4 acc = h4[(size_t)c * 4 + q];          // self: g~[c] = dc*g[c]
    int k0 = start[c];
    int k1 = k0 + cnt[c];
    for (int k = k0; k < k1; ++k) {
        int r = rows_sorted[k];
        float4 v = h4[(size_t)r * 4 + q];
        acc.x += v.x; acc.y += v.y; acc.z += v.z; acc.w += v.w;
    }
    acc.x *= dc; acc.y *= dc; acc.z *= dc; acc.w *= dc;
    ((float4*)t)[(size_t)c * 4 + q] = acc;
}

// ------- fused: out = log_softmax(t @ W2 + s*b2^T), wave per node ---------
__global__ void mm2lsm_kernel(const float* __restrict__ t, const float* __restrict__ s,
                              const float* __restrict__ W2, const float* __restrict__ b2,
                              float* __restrict__ out) {
    __shared__ float w2s[F1 * F2];   // 640
    __shared__ float b2s[F2];
    __shared__ float ts[4 * F1];     // 4 nodes x 16
    int tid = threadIdx.x;
    for (int i = tid; i < F1 * F2; i += 256) w2s[i] = W2[i];
    if (tid < F2) b2s[tid] = b2[tid];
    int nodeBase = blockIdx.x * 4;
    if (tid < 4 * F1) ts[tid] = t[(size_t)nodeBase * F1 + tid];
    __syncthreads();
    int w    = tid >> 6;
    int lane = tid & 63;
    int c = nodeBase + w;
    float sc = s[c];
    float v = -INFINITY;
    if (lane < F2) {
        float acc = sc * b2s[lane];
#pragma unroll
        for (int k = 0; k < F1; ++k)
            acc = fmaf(ts[w * F1 + k], w2s[k * F2 + lane], acc);
        v = acc;
    }
    float m = v;
#pragma unroll
    for (int off = 32; off; off >>= 1)
        m = fmaxf(m, __shfl_xor(m, off, 64));
    float ex = (lane < F2) ? expf(v - m) : 0.0f;
    float ssum = ex;
#pragma unroll
    for (int off = 32; off; off >>= 1)
        ssum += __shfl_xor(ssum, off, 64);
    if (lane < F2) out[(size_t)c * F2 + lane] = v - m - logf(ssum);
}

extern "C" void kernel_launch(void* const* d_in, const int* in_sizes, int n_in,
                              void* d_out, int out_size, void* d_ws, size_t ws_size,
                              hipStream_t stream) {
    const float* x   = (const float*)d_in[0];
    const int*   ei  = (const int*)d_in[1];
    const float* W1  = (const float*)d_in[2];
    const float* b1  = (const float*)d_in[3];
    const float* W2  = (const float*)d_in[4];
    const float* b2  = (const float*)d_in[5];
    float* out = (float*)d_out;

    const int* row = ei;             // edge_index[0]
    const int* col = ei + N_EDGES;   // edge_index[1]

    // workspace layout, 4B words, P = 102400; total ~39.9 MB
    const size_t P = 102400;
    float* fws = (float*)d_ws;
    float* dis = fws;                            // P
    float* s   = dis + P;                        // P
    int* start = (int*)(s + P);                  // P
    int* cnt   = start + P;                      // P
    int* deg   = cnt + P;                        // P
    int* bucket_start = deg + P;                 // 8192
    int* bcur  = bucket_start + 8192;            // 51200 (6250*8 used)
    int* ocur  = bcur + 51200;                   // 8192
    int* rows_sorted = ocur + 8192;              // N_EDGES = 3.2M words
    int* staging_o   = rows_sorted + N_EDGES;    // 6250*32 = 200K words
    int* staging     = staging_o + (size_t)N_BUCKETS * OCAP;  // 6250*8*120 = 6.0M words
    // staging region reused after csr_kernel: h1t (16P), t (16P), g (16P) = 4.9M words
    float* h1t = (float*)staging;
    float* t   = (float*)staging + 16 * P;
    float* g   = (float*)staging + 32 * P;

    const int B = 256;
    const int gridE = (N_EDGES + B - 1) / B;

    // ---- graph build: partitioned bucket-bin once, then local histograms ----
    init_kernel<<<(int)((P + B - 1) / B), B, 0, stream>>>(deg, bcur, ocur);
    bin_kernel<<<gridE, B, 0, stream>>>(row, col, deg, bcur, ocur, staging, staging_o);
    dis_kernel<<<(N_NODES + B - 1) / B, B, 0, stream>>>(deg, dis);
    scanb_kernel<<<1, 256, 0, stream>>>(bcur, ocur, bucket_start);
    csr_kernel<<<N_BUCKETS, B, 0, stream>>>(staging, staging_o, bcur, ocur,
                                            bucket_start, start, cnt, rows_sorted);

    // ---- layer 1: h1t = dis*(x@W1+b1) ; g~ = dis*relu(dis*A-sum) --------
    mm1_kernel<<<(N_NODES + BR - 1) / BR, B, 0, stream>>>(x, W1, b1, dis, h1t);
    agg1_kernel<<<(N_NODES * 4 + B - 1) / B, B, 0, stream>>>(
        rows_sorted, start, cnt, dis, h1t, g, s);

    // ---- layer 2 (W2 commuted past aggregation): t = A_hat g~ -----------
    agg2_kernel<<<(N_NODES * 4 + B - 1) / B, B, 0, stream>>>(
        rows_sorted, start, cnt, dis, g, t);

    // ---- out = log_softmax(t@W2 + s*b2) ----
    mm2lsm_kernel<<<N_NODES / 4, B, 0, stream>>>(t, s, W2, b2, out);
}

// Round 2
// 868.654 us; speedup vs baseline: 1.0130x; 1.0096x over previous
//
#include <hip/hip_runtime.h>
#include <math.h>

#define N_NODES 100000
#define N_EDGES 3200000
#define F_IN    512
#define F1      16
#define F2      40

#define N_BUCKETS 6250    // node>>4 buckets; 6250*16 == 100000 exactly
#define NPART     8       // writer partitions == physical XCDs (via HW_REG_XCC_ID)
#define CAPP      120     // per (part,bucket) capacity; mean 64, sigma 8 -> 7 sigma
#define OCAP      64      // per-bucket overflow segment (shared across parts)

// mm1 tiling
#define BR 256            // rows per block
#define KK 32             // k-chunk
#define XPITCH 36         // 32 + 4 pad: 2-way LDS alias max (free)

__device__ __forceinline__ int xcc_id() {
    unsigned x;
    asm volatile("s_getreg_b32 %0, hwreg(HW_REG_XCC_ID)" : "=s"(x));
    return (int)(x & (NPART - 1));
}

// ------- layer-1 matmul, LDS-tiled: h1t[r] = dis[r]*(x[r]@W1 + b1) -------
__global__ __launch_bounds__(256, 4) void mm1_kernel(
        const float* __restrict__ x, const float* __restrict__ W1,
        const float* __restrict__ b1, const float* __restrict__ dis,
        float* __restrict__ h1t) {
    __shared__ float xs[BR * XPITCH];     // 36 KB
    __shared__ float ws[KK * F1];         // 2 KB
    int t = threadIdx.x;
    int rbase = blockIdx.x * BR;
    int jq = t & 3;            // j-quad: cols jq*4..jq*4+3
    int rg = t >> 2;           // row-group 0..63: rows rg*4..rg*4+3
    float acc[4][4];
#pragma unroll
    for (int i = 0; i < 4; ++i)
#pragma unroll
        for (int j = 0; j < 4; ++j) acc[i][j] = 0.0f;

    for (int ch = 0; ch < F_IN / KK; ++ch) {
        int c0 = ch * KK;
#pragma unroll
        for (int i = 0; i < 8; ++i) {
            int p  = t + i * 256;
            int tr = p >> 3;
            int f4 = p & 7;
            float4 v = make_float4(0.0f, 0.0f, 0.0f, 0.0f);
            int grow = rbase + tr;
            if (grow < N_NODES)
                v = *(const float4*)(x + (size_t)grow * F_IN + c0 + f4 * 4);
            *(float4*)&xs[tr * XPITCH + f4 * 4] = v;
        }
        if (t < 128) {
            int kk = t >> 2, f4 = t & 3;
            *(float4*)&ws[kk * F1 + f4 * 4] =
                *(const float4*)(W1 + (size_t)(c0 + kk) * F1 + f4 * 4);
        }
        __syncthreads();
#pragma unroll
        for (int k4 = 0; k4 < KK / 4; ++k4) {
            float xa[4][4], wa[4][4];
#pragma unroll
            for (int i = 0; i < 4; ++i)
                *(float4*)&xa[i][0] =
                    *(const float4*)&xs[(rg * 4 + i) * XPITCH + k4 * 4];
#pragma unroll
            for (int m = 0; m < 4; ++m)
                *(float4*)&wa[m][0] =
                    *(const float4*)&ws[(k4 * 4 + m) * F1 + jq * 4];
#pragma unroll
            for (int i = 0; i < 4; ++i)
#pragma unroll
                for (int m = 0; m < 4; ++m)
#pragma unroll
                    for (int j = 0; j < 4; ++j)
                        acc[i][j] = fmaf(xa[i][m], wa[m][j], acc[i][j]);
        }
        __syncthreads();
    }

    float4 bv = *(const float4*)(b1 + jq * 4);
#pragma unroll
    for (int i = 0; i < 4; ++i) {
        int grow = rbase + rg * 4 + i;
        if (grow < N_NODES) {
            float d = dis[grow];
            float4 o;
            o.x = d * (acc[i][0] + bv.x);
            o.y = d * (acc[i][1] + bv.y);
            o.z = d * (acc[i][2] + bv.z);
            o.w = d * (acc[i][3] + bv.w);
            *(float4*)(h1t + (size_t)grow * F1 + jq * 4) = o;
        }
    }
}

// ---------------- init: zero deg8 + cursors ------------------------------
__global__ void init_kernel(int* __restrict__ deg8, int* __restrict__ bcur,
                            int* __restrict__ ocur) {
    int i = blockIdx.x * blockDim.x + threadIdx.x;
    if (i < NPART * 102400) deg8[i] = 0;
    if (i < N_BUCKETS * NPART) bcur[i] = 0;
    if (i < N_BUCKETS) ocur[i] = 0;
}

// ---- single pass: bin edges by col>>4 (payload r|low4(c)) into staging
// partitioned by the PHYSICAL XCD id (s_getreg HW_REG_XCC_ID). All hot
// structures (cursors bcur[part][bucket], staging[part][bucket][CAPP],
// degree counters deg8[part][node]) are single-XCD-owned, so their dirty
// lines stay resident in one L2 instead of bouncing across 8 incoherent
// L2s (R0/R1 counters: ~one 64B eviction PER EDGE = ownership churn).
__global__ void bin_kernel(const int* __restrict__ row, const int* __restrict__ col,
                           int* __restrict__ deg8,
                           int* __restrict__ bcur, int* __restrict__ ocur,
                           int* __restrict__ staging, int* __restrict__ staging_o) {
    int e = blockIdx.x * blockDim.x + threadIdx.x;
    if (e >= N_EDGES) return;
    int part = xcc_id();
    int r = row[e];
    int c = col[e];
    atomicAdd(&deg8[part * 102400 + r], 1);
    int bc = c >> 4;
    int payload = r | ((c & 15) << 27);
    int cell = part * N_BUCKETS + bc;
    int pc = atomicAdd(&bcur[cell], 1);
    if (pc < CAPP) {
        staging[(size_t)cell * CAPP + pc] = payload;
    } else {
        int po = atomicAdd(&ocur[bc], 1);
        if (po < OCAP) staging_o[(size_t)bc * OCAP + po] = payload;
    }
}

// ---- dis = (deg+1)^-0.5 (+1 self loop); deg = sum of 8 per-XCD copies ---
__global__ void dis_kernel(const int* __restrict__ deg8, float* __restrict__ dis) {
    int i = blockIdx.x * blockDim.x + threadIdx.x;
    if (i < N_NODES) {
        int d = 1;
#pragma unroll
        for (int p = 0; p < NPART; ++p) d += deg8[p * 102400 + i];
        dis[i] = rsqrtf((float)d);
    }
}

// ---- exclusive scan of 6250 bucket sizes -> bucket_start (one block) ----
__global__ void scanb_kernel(const int* __restrict__ bcur, const int* __restrict__ ocur,
                             int* __restrict__ bucket_start) {
    __shared__ int lds[256];
    int t = threadIdx.x;
    int base = t * 25;                 // 256*25 = 6400 >= 6250
    int s = 0;
    for (int i = 0; i < 25; ++i) {
        int idx = base + i;
        if (idx < N_BUCKETS) {
            int tot = min(ocur[idx], OCAP);
#pragma unroll
            for (int p = 0; p < NPART; ++p) tot += min(bcur[p * N_BUCKETS + idx], CAPP);
            s += tot;
        }
    }
    lds[t] = s;
    __syncthreads();
    for (int off = 1; off < 256; off <<= 1) {
        int v = (t >= off) ? lds[t - off] : 0;
        __syncthreads();
        lds[t] += v;
        __syncthreads();
    }
    int run = lds[t] - s;              // exclusive prefix
    for (int i = 0; i < 25; ++i) {
        int idx = base + i;
        if (idx < N_BUCKETS) {
            bucket_start[idx] = run;
            int tot = min(ocur[idx], OCAP);
#pragma unroll
            for (int p = 0; p < NPART; ++p) tot += min(bcur[p * N_BUCKETS + idx], CAPP);
            run += tot;
        }
    }
}

// ---- per-bucket CSR finalize: 16-bin LDS histogram + scan + scatter -----
__global__ void csr_kernel(const int* __restrict__ staging, const int* __restrict__ staging_o,
                           const int* __restrict__ bcur, const int* __restrict__ ocur,
                           const int* __restrict__ bucket_start,
                           int* __restrict__ start, int* __restrict__ cnt,
                           int* __restrict__ rows_sorted) {
    __shared__ int cnt16[16], off16[16], cur16[16];
    int b = blockIdx.x, t = threadIdx.x;
    if (t < 16) cnt16[t] = 0;
    __syncthreads();
    int szs[NPART];
#pragma unroll
    for (int p = 0; p < NPART; ++p) szs[p] = min(bcur[p * N_BUCKETS + b], CAPP);
    int szo = min(ocur[b], OCAP);
    const int* so = staging_o + (size_t)b * OCAP;
#pragma unroll
    for (int p = 0; p < NPART; ++p) {
        const int* sb = staging + (size_t)(p * N_BUCKETS + b) * CAPP;
        for (int k = t; k < szs[p]; k += 256)
            atomicAdd(&cnt16[(sb[k] >> 27) & 15], 1);
    }
    for (int k = t; k < szo; k += 256)
        atomicAdd(&cnt16[(so[k] >> 27) & 15], 1);
    __syncthreads();
    if (t == 0) {
        int s = 0;
#pragma unroll
        for (int i = 0; i < 16; ++i) { off16[i] = s; s += cnt16[i]; }
    }
    __syncthreads();
    int base = bucket_start[b];
    if (t < 16) {
        start[b * 16 + t] = base + off16[t];
        cnt[b * 16 + t]   = cnt16[t];
        cur16[t] = 0;
    }
    __syncthreads();
#pragma unroll
    for (int p = 0; p < NPART; ++p) {
        const int* sb = staging + (size_t)(p * N_BUCKETS + b) * CAPP;
        for (int k = t; k < szs[p]; k += 256) {
            int entry = sb[k];
            int c4 = (entry >> 27) & 15;
            int pos = atomicAdd(&cur16[c4], 1);
            rows_sorted[base + off16[c4] + pos] = entry & 0x07FFFFFF;
        }
    }
    for (int k = t; k < szo; k += 256) {
        int entry = so[k];
        int c4 = (entry >> 27) & 15;
        int pos = atomicAdd(&cur16[c4], 1);
        rows_sorted[base + off16[c4] + pos] = entry & 0x07FFFFFF;
    }
}

// ------- layer-1 aggregation (dis-folded) + relu + row-sum s -------------
__global__ void agg1_kernel(const int* __restrict__ rows_sorted,
                            const int* __restrict__ start, const int* __restrict__ cnt,
                            const float* __restrict__ dis, const float* __restrict__ h1t,
                            float* __restrict__ g, float* __restrict__ s_out) {
    int idx = blockIdx.x * blockDim.x + threadIdx.x;
    if (idx >= N_NODES * 4) return;
    int c = idx >> 2;
    int q = idx & 3;
    float dc = dis[c];
    const float4* h4 = (const float4*)h1t;
    float4 acc = h4[(size_t)c * 4 + q];          // self loop: h1t[c] = dc*h1[c]
    float ss = dc;
    int k0 = start[c];
    int k1 = k0 + cnt[c];
    for (int k = k0; k < k1; ++k) {
        int r = rows_sorted[k];
        float4 v = h4[(size_t)r * 4 + q];
        acc.x += v.x; acc.y += v.y; acc.z += v.z; acc.w += v.w;
        if (q == 0) ss += dis[r];                // lane q=0 gathers dis (L2-hot)
    }
    acc.x = dc * fmaxf(acc.x * dc, 0.0f);        // relu, then fold dc for layer 2
    acc.y = dc * fmaxf(acc.y * dc, 0.0f);
    acc.z = dc * fmaxf(acc.z * dc, 0.0f);
    acc.w = dc * fmaxf(acc.w * dc, 0.0f);
    ((float4*)g)[(size_t)c * 4 + q] = acc;
    if (q == 0) s_out[c] = dc * ss;              // s = (A_hat . 1)[c]
}

// ---------------- layer-2 aggregation (dis-folded): t = A_hat g ----------
__global__ void agg2_kernel(const int* __restrict__ rows_sorted,
                            const int* __restrict__ start, const int* __restrict__ cnt,
                            const float* __restrict__ dis, const float* __restrict__ g,
                            float* __restrict__ t) {
    int idx = blockIdx.x * blockDim.x + threadIdx.x;
    if (idx >= N_NODES * 4) return;
    int c = idx >> 2;
    int q = idx & 3;
    float dc = dis[c];
    const float4* h4 = (const float4*)g;
    float4 acc = h4[(size_t)c * 4 + q];          // self: g~[c] = dc*g[c]
    int k0 = start[c];
    int k1 = k0 + cnt[c];
    for (int k = k0; k < k1; ++k) {
        int r = rows_sorted[k];
        float4 v = h4[(size_t)r * 4 + q];
        acc.x += v.x; acc.y += v.y; acc.z += v.z; acc.w += v.w;
    }
    acc.x *= dc; acc.y *= dc; acc.z *= dc; acc.w *= dc;
    ((float4*)t)[(size_t)c * 4 + q] = acc;
}

// ------- fused: out = log_softmax(t @ W2 + s*b2^T), wave per node ---------
__global__ void mm2lsm_kernel(const float* __restrict__ t, const float* __restrict__ s,
                              const float* __restrict__ W2, const float* __restrict__ b2,
                              float* __restrict__ out) {
    __shared__ float w2s[F1 * F2];   // 640
    __shared__ float b2s[F2];
    __shared__ float ts[4 * F1];     // 4 nodes x 16
    int tid = threadIdx.x;
    for (int i = tid; i < F1 * F2; i += 256) w2s[i] = W2[i];
    if (tid < F2) b2s[tid] = b2[tid];
    int nodeBase = blockIdx.x * 4;
    if (tid < 4 * F1) ts[tid] = t[(size_t)nodeBase * F1 + tid];
    __syncthreads();
    int w    = tid >> 6;
    int lane = tid & 63;
    int c = nodeBase + w;
    float sc = s[c];
    float v = -INFINITY;
    if (lane < F2) {
        float acc = sc * b2s[lane];
#pragma unroll
        for (int k = 0; k < F1; ++k)
            acc = fmaf(ts[w * F1 + k], w2s[k * F2 + lane], acc);
        v = acc;
    }
    float m = v;
#pragma unroll
    for (int off = 32; off; off >>= 1)
        m = fmaxf(m, __shfl_xor(m, off, 64));
    float ex = (lane < F2) ? expf(v - m) : 0.0f;
    float ssum = ex;
#pragma unroll
    for (int off = 32; off; off >>= 1)
        ssum += __shfl_xor(ssum, off, 64);
    if (lane < F2) out[(size_t)c * F2 + lane] = v - m - logf(ssum);
}

extern "C" void kernel_launch(void* const* d_in, const int* in_sizes, int n_in,
                              void* d_out, int out_size, void* d_ws, size_t ws_size,
                              hipStream_t stream) {
    const float* x   = (const float*)d_in[0];
    const int*   ei  = (const int*)d_in[1];
    const float* W1  = (const float*)d_in[2];
    const float* b1  = (const float*)d_in[3];
    const float* W2  = (const float*)d_in[4];
    const float* b2  = (const float*)d_in[5];
    float* out = (float*)d_out;

    const int* row = ei;             // edge_index[0]
    const int* col = ei + N_EDGES;   // edge_index[1]

    // workspace layout, 4B words, P = 102400; total ~40.3 MB
    const size_t P = 102400;
    float* fws = (float*)d_ws;
    float* dis = fws;                            // P
    float* s   = dis + P;                        // P
    int* start = (int*)(s + P);                  // P
    int* cnt   = start + P;                      // P
    int* bucket_start = cnt + P;                 // 8192
    int* bcur  = bucket_start + 8192;            // 51200 (8*6250 used)
    int* ocur  = bcur + 51200;                   // 8192
    int* rows_sorted = ocur + 8192;              // N_EDGES = 3.2M words
    int* staging_o   = rows_sorted + N_EDGES;    // 6250*64 = 400K words
    int* staging     = staging_o + (size_t)N_BUCKETS * OCAP;  // 8*6250*120 = 6.0M words
    // deg8 (8P = 819200 words) aliases rows_sorted: dead before csr writes it
    int* deg8 = rows_sorted;
    // staging region reused after csr_kernel: h1t (16P), t (16P), g (16P) = 4.9M words
    float* h1t = (float*)staging;
    float* t   = (float*)staging + 16 * P;
    float* g   = (float*)staging + 32 * P;

    const int B = 256;
    const int gridE = (N_EDGES + B - 1) / B;

    // ---- graph build: XCD-partitioned bucket-bin, then local histograms ----
    init_kernel<<<(NPART * (int)P + B - 1) / B, B, 0, stream>>>(deg8, bcur, ocur);
    bin_kernel<<<gridE, B, 0, stream>>>(row, col, deg8, bcur, ocur, staging, staging_o);
    dis_kernel<<<(N_NODES + B - 1) / B, B, 0, stream>>>(deg8, dis);
    scanb_kernel<<<1, 256, 0, stream>>>(bcur, ocur, bucket_start);
    csr_kernel<<<N_BUCKETS, B, 0, stream>>>(staging, staging_o, bcur, ocur,
                                            bucket_start, start, cnt, rows_sorted);

    // ---- layer 1: h1t = dis*(x@W1+b1) ; g~ = dis*relu(dis*A-sum) --------
    mm1_kernel<<<(N_NODES + BR - 1) / BR, B, 0, stream>>>(x, W1, b1, dis, h1t);
    agg1_kernel<<<(N_NODES * 4 + B - 1) / B, B, 0, stream>>>(
        rows_sorted, start, cnt, dis, h1t, g, s);

    // ---- layer 2 (W2 commuted past aggregation): t = A_hat g~ -----------
    agg2_kernel<<<(N_NODES * 4 + B - 1) / B, B, 0, stream>>>(
        rows_sorted, start, cnt, dis, g, t);

    // ---- out = log_softmax(t@W2 + s*b2) ----
    mm2lsm_kernel<<<N_NODES / 4, B, 0, stream>>>(t, s, W2, b2, out);
}